// Round 11
// baseline (73.624 us; speedup 1.0000x reference)
//
#include <hip/hip_runtime.h>

// SparseSelfAttention, algebraically reduced:
//   out[hd] = sum_g c_g * softmax(Q_hd K_g^T / 16) @ Vs[(2hd-g)%4]
//   Vs[head][j] = sum_{w=-2..2} v[head][(j+2w)%N]
//   c_g = 2 if (hd-g)%4==2 else 1
// N=2304 tokens, 4 heads, dh=64.
//
// k_flash v6: K in LDS (dbuf 2x8KB, global_load_lds w16, counted vmcnt),
// V DIRECT global->register (VF is L2-resident + fragment-major coalesced;
// staging it was pure overhead -- m169 pattern), 2 query-strips per wave,
// per-c fused QK->exp2->pack to cap live registers, softmax denom via
// ones-row MFMA. setprio REMOVED (barrier-lockstep waves = m190 regime).
// k_convert fused into k_proj (inline f32->f16 cvt_pkrtz).
// R5: no waves-per-EU clamp. R6: VGPR < 128 target. R8: cvt_pkrtz is __fp16.

#define N_TOK 2304
#define OUTC 256
#define HSZ (N_TOK * 64)   // halfs per head = 147456

typedef _Float16 half8 __attribute__((ext_vector_type(8)));
typedef _Float16 half4 __attribute__((ext_vector_type(4)));
typedef __fp16 fp16x2 __attribute__((ext_vector_type(2)));
typedef float f32x4 __attribute__((ext_vector_type(4)));

typedef __attribute__((address_space(3))) unsigned int as3_u32;
typedef __attribute__((address_space(1))) unsigned int as1_u32;

__device__ __forceinline__ f32x4 mfma16(half8 a, half8 b, f32x4 c) {
  return __builtin_amdgcn_mfma_f32_16x16x32_f16(a, b, c, 0, 0, 0);
}

__device__ __forceinline__ void gload_lds16(const _Float16* g, _Float16* l) {
  __builtin_amdgcn_global_load_lds((const as1_u32*)g, (as3_u32*)l, 16, 0, 0);
}

union H8U { half8 h8; fp16x2 h2[4]; };

__device__ __forceinline__ half8 pack_f32x8(const float* e) {
  H8U u;
  u.h2[0] = __builtin_amdgcn_cvt_pkrtz(e[0], e[1]);
  u.h2[1] = __builtin_amdgcn_cvt_pkrtz(e[2], e[3]);
  u.h2[2] = __builtin_amdgcn_cvt_pkrtz(e[4], e[5]);
  u.h2[3] = __builtin_amdgcn_cvt_pkrtz(e[6], e[7]);
  return u.h8;
}

// ---- kernel 1: QKV projection (reads f32 x/W directly, converts inline) ----
// mat 0 -> Qh[hd][n][d] row-major, scaled by log2(e)/16 (exp2-domain softmax)
// mat 1 -> KF fragment-major: KF[hd*HSZ + ((t*4+c)*2+h)*512 + (g4*16+lr)*8 + ii]
//          = K[hd][t*64+16c+lr][32h+8*g4+ii]
// mat 2 -> VfT[o][n] f32 row-major
__global__ __launch_bounds__(256) void k_proj(
    const float* __restrict__ x, const float* __restrict__ Wq,
    const float* __restrict__ Wk, const float* __restrict__ Wv,
    const float* __restrict__ bq, const float* __restrict__ bk,
    const float* __restrict__ bv,
    _Float16* __restrict__ Qh, _Float16* __restrict__ KF, float* __restrict__ VfT) {
  const int w = threadIdx.x >> 6, lane = threadIdx.x & 63;
  const int lr = lane & 15, lk = lane >> 4;
  const int n0 = blockIdx.x * 64 + w * 16;
  const int o0 = blockIdx.y * 64;
  const int mat = blockIdx.z;
  const float* W = (mat == 0) ? Wq : (mat == 1) ? Wk : Wv;
  f32x4 acc[4] = {};
  const float* xrow = x + (size_t)(n0 + lr) * OUTC + 8 * lk;
#pragma unroll
  for (int kk = 0; kk < 8; ++kk) {
    float af[8];
    *(float4*)&af[0] = *(const float4*)(xrow + 32 * kk);
    *(float4*)&af[4] = *(const float4*)(xrow + 32 * kk + 4);
    half8 a = pack_f32x8(af);
#pragma unroll
    for (int c = 0; c < 4; ++c) {
      const float* wrow = W + (size_t)(o0 + 16*c + lr) * OUTC + 32*kk + 8*lk;
      float bf[8];
      *(float4*)&bf[0] = *(const float4*)(wrow);
      *(float4*)&bf[4] = *(const float4*)(wrow + 4);
      half8 b = pack_f32x8(bf);
      acc[c] = mfma16(a, b, acc[c]);
    }
  }
  const float* bias = (mat == 0) ? bq : (mat == 1) ? bk : bv;
  const int hd = blockIdx.y;   // head for mat 0/1
#pragma unroll
  for (int c = 0; c < 4; ++c) {
    int o = o0 + 16*c + lr;
    float bo = bias[o];
    if (mat == 2) {
      float4 vv;
      vv.x = acc[c][0] + bo; vv.y = acc[c][1] + bo;
      vv.z = acc[c][2] + bo; vv.w = acc[c][3] + bo;
      *(float4*)(VfT + (size_t)o * N_TOK + n0 + 4*lk) = vv;
    } else if (mat == 0) {
      int d = 16*c + lr;
      const float qs = 0.0625f * 1.4426950408889634f;   // (1/16) * log2(e)
#pragma unroll
      for (int r = 0; r < 4; ++r) {
        int n = n0 + 4*lk + r;
        Qh[((size_t)hd * N_TOK + n) * 64 + d] = (_Float16)((acc[c][r] + bo) * qs);
      }
    } else {
      int d = 16*c + lr;
      int h = d >> 5, g4K = (d >> 3) & 3, iiK = d & 7;
#pragma unroll
      for (int r = 0; r < 4; ++r) {
        int n = n0 + 4*lk + r;
        int tK = n >> 6, cK = (n >> 4) & 3, lrK = n & 15;
        KF[(size_t)hd * HSZ + ((tK*4 + cK)*2 + h)*512 + (g4K*16 + lrK)*8 + iiK] =
            (_Float16)(acc[c][r] + bo);
      }
    }
  }
}

// ---- kernel 2: smooth V over w-shifts, emit fragment-major + k-slot-permuted ----
// VF[vh*HSZ + t*4096 + f*8 + i]  (f = cc*128 + h*64 + g4*16 + lr)
//   = Vs[vh][16cc+lr][ t*64 + 32h + 16*(i>>2) + 4*g4 + (i&3) ]
__global__ __launch_bounds__(256) void k_smooth(
    const float* __restrict__ VfT, _Float16* __restrict__ VF) {
  const int t = blockIdx.x, vh = blockIdx.y;
  for (int f = threadIdx.x; f < 512; f += 256) {
    int cc = f >> 7, h = (f >> 6) & 1, g4 = (f >> 4) & 3, lr = f & 15;
    const float* src = VfT + (size_t)(vh*64 + 16*cc + lr) * N_TOK;
    int jbase = t*64 + 32*h + 4*g4;
    half8 out;
#pragma unroll
    for (int i = 0; i < 8; ++i) {
      int j = jbase + 16*(i >> 2) + (i & 3);
      float s = 0.f;
#pragma unroll
      for (int w = -4; w <= 4; w += 2) s += src[(j + w + N_TOK) % N_TOK];
      out[i] = (_Float16)s;
    }
    *(half8*)(VF + (size_t)vh * HSZ + (size_t)t * 4096 + f * 8) = out;
  }
}

// ---- kernel 3: flash attention, K-LDS + V-direct, split-K x4 ----
__global__ __launch_bounds__(256) void k_flash(
    const _Float16* __restrict__ Qh, const _Float16* __restrict__ KF,
    const _Float16* __restrict__ VF,
    _Float16* __restrict__ Opart, float* __restrict__ Lpart) {
  __shared__ __align__(16) _Float16 ldsK[2][4096];   // 8 KB per buffer
  const int wv = threadIdx.x >> 6, lane = threadIdx.x & 63;
  const int lr = lane & 15, g4 = lane >> 4;
  const int strip = blockIdx.x * 4 + wv;      // 0..71, 32 queries each
  const int n0 = strip * 32;
  const int pair = blockIdx.y;                // hd*4 + gk
  const int hd = pair >> 2, gk = pair & 3;
  const int chunk = blockIdx.z;               // 9 tiles each
  const int vh = (2*hd + 4 - gk) & 3;

  const _Float16* Qp = Qh + ((size_t)hd * N_TOK + n0 + lr) * 64 + 8*g4;
  const half8 qa0 = *(const half8*)(Qp);
  const half8 qa1 = *(const half8*)(Qp + 32);
  const half8 qb0 = *(const half8*)(Qp + 16*64);
  const half8 qb1 = *(const half8*)(Qp + 16*64 + 32);

  // K staged to LDS: each wave stages one 2KB quarter of the 8KB tile
  const _Float16* Ktg = KF + (size_t)gk * HSZ + (size_t)chunk * 9 * 4096
                        + wv * 1024 + lane * 8;
  // V read direct from global (L2-resident), fragment-major coalesced
  const _Float16* Vb = VF + (size_t)vh * HSZ + (size_t)chunk * 9 * 4096 + lane * 8;

  f32x4 accA[4] = {}, accB[4] = {};
  f32x4 acclA = {}, acclB = {};
  half8 ones;
#pragma unroll
  for (int i = 0; i < 8; ++i) ones[i] = (_Float16)1.0f;

  auto stageK = [&](int t, int b) {
    const _Float16* s = Ktg + (size_t)t * 4096;
    _Float16* d = &ldsK[b][wv * 1024];
    gload_lds16(s, d);
    gload_lds16(s + 512, d + 512);
  };

  stageK(0, 0);
#pragma unroll 1
  for (int t = 0; t < 9; ++t) {
    if (t < 8) stageK(t + 1, (t + 1) & 1);
    // V batch 1 (cc=0,1) issued early: QK+exp (~400cyc) covers L2 latency
    const _Float16* Vt = Vb + (size_t)t * 4096;
    half8 v0 = *(const half8*)(Vt);
    half8 v1 = *(const half8*)(Vt + 512);
    half8 v2 = *(const half8*)(Vt + 1024);
    half8 v3 = *(const half8*)(Vt + 1536);
    __builtin_amdgcn_sched_barrier(0);
    // counted wait: only our own stage(t) K loads must have landed;
    // stage(t+1) [2] + V batch1 [4] stay in flight across the barrier
    if (t < 8) asm volatile("s_waitcnt vmcnt(6)" ::: "memory");
    else       asm volatile("s_waitcnt vmcnt(4)" ::: "memory");
    __builtin_amdgcn_sched_barrier(0);
    __builtin_amdgcn_s_barrier();        // all waves' K(t) in LDS
    __builtin_amdgcn_sched_barrier(0);

    // QK + exp2 + pack, fused per-c to keep live registers small
    const _Float16* ldsKb = &ldsK[t & 1][0] + lane * 8;
    H8U a0, a1, b0, b1;
#pragma unroll
    for (int c = 0; c < 4; ++c) {
      half8 k0 = *(const half8*)(ldsKb + c*1024);
      half8 k1 = *(const half8*)(ldsKb + c*1024 + 512);
      f32x4 tA = {}; tA = mfma16(k0, qa0, tA); tA = mfma16(k1, qa1, tA);
      f32x4 tB = {}; tB = mfma16(k0, qb0, tB); tB = mfma16(k1, qb1, tB);
      float eA0 = __builtin_amdgcn_exp2f(tA[0]);
      float eA1 = __builtin_amdgcn_exp2f(tA[1]);
      float eA2 = __builtin_amdgcn_exp2f(tA[2]);
      float eA3 = __builtin_amdgcn_exp2f(tA[3]);
      float eB0 = __builtin_amdgcn_exp2f(tB[0]);
      float eB1 = __builtin_amdgcn_exp2f(tB[1]);
      float eB2 = __builtin_amdgcn_exp2f(tB[2]);
      float eB3 = __builtin_amdgcn_exp2f(tB[3]);
      H8U* da = (c < 2) ? &a0 : &a1;
      H8U* db = (c < 2) ? &b0 : &b1;
      int base = (c & 1) * 2;
      da->h2[base]     = __builtin_amdgcn_cvt_pkrtz(eA0, eA1);
      da->h2[base + 1] = __builtin_amdgcn_cvt_pkrtz(eA2, eA3);
      db->h2[base]     = __builtin_amdgcn_cvt_pkrtz(eB0, eB1);
      db->h2[base + 1] = __builtin_amdgcn_cvt_pkrtz(eB2, eB3);
    }
    // V batch 2 (cc=2,3): issued now, covered by remaining exp/pack + PV cc01
    half8 v4 = *(const half8*)(Vt + 2048);
    half8 v5 = *(const half8*)(Vt + 2560);
    half8 v6 = *(const half8*)(Vt + 3072);
    half8 v7 = *(const half8*)(Vt + 3584);

    // PV from register V
    accA[0] = mfma16(v0, a0.h8, accA[0]); accA[0] = mfma16(v1, a1.h8, accA[0]);
    accB[0] = mfma16(v0, b0.h8, accB[0]); accB[0] = mfma16(v1, b1.h8, accB[0]);
    accA[1] = mfma16(v2, a0.h8, accA[1]); accA[1] = mfma16(v3, a1.h8, accA[1]);
    accB[1] = mfma16(v2, b0.h8, accB[1]); accB[1] = mfma16(v3, b1.h8, accB[1]);
    accA[2] = mfma16(v4, a0.h8, accA[2]); accA[2] = mfma16(v5, a1.h8, accA[2]);
    accB[2] = mfma16(v4, b0.h8, accB[2]); accB[2] = mfma16(v5, b1.h8, accB[2]);
    accA[3] = mfma16(v6, a0.h8, accA[3]); accA[3] = mfma16(v7, a1.h8, accA[3]);
    accB[3] = mfma16(v6, b0.h8, accB[3]); accB[3] = mfma16(v7, b1.h8, accB[3]);
    acclA = mfma16(ones, a0.h8, acclA); acclA = mfma16(ones, a1.h8, acclA);
    acclB = mfma16(ones, b0.h8, acclB); acclB = mfma16(ones, b1.h8, acclB);

    if (t < 8) {
      __builtin_amdgcn_sched_barrier(0);
      __builtin_amdgcn_s_barrier();      // ldsK[t&1] safe before stage(t+2)
    }
  }

  // epilogue: accl[0] is the full per-query denom (identical across r and g4)
  float invA = 1.0f / acclA[0];
  float invB = 1.0f / acclB[0];
  _Float16* Oa = Opart + (((size_t)chunk * 16 + pair) * N_TOK + n0 + lr) * 64;
  _Float16* Ob = Oa + 16 * 64;
#pragma unroll
  for (int cc = 0; cc < 4; ++cc) {
    half4 ha, hb;
#pragma unroll
    for (int r = 0; r < 4; ++r) {
      ha[r] = (_Float16)(accA[cc][r] * invA);
      hb[r] = (_Float16)(accB[cc][r] * invB);
    }
    *(half4*)(Oa + 16*cc + 4*g4) = ha;
    *(half4*)(Ob + 16*cc + 4*g4) = hb;
  }
  if (g4 == 0) {
    Lpart[((size_t)chunk * 16 + pair) * N_TOK + n0 + lr] = acclA[0];
    Lpart[((size_t)chunk * 16 + pair) * N_TOK + n0 + 16 + lr] = acclB[0];
  }
}

// ---- kernel 4: merge split-K chunks (l-weighted), weight by c_g, sum over gk ----
__global__ __launch_bounds__(256) void k_combine(
    const _Float16* __restrict__ Opart, const float* __restrict__ Lpart,
    float* __restrict__ out) {
  int gid = blockIdx.x * 256 + threadIdx.x;   // 73728 total
  int hd = gid / (N_TOK * 8);
  int rem = gid % (N_TOK * 8);
  int n = rem >> 3, db = (rem & 7) * 8;
  float acc[8] = {};
#pragma unroll
  for (int gk = 0; gk < 4; ++gk) {
    float cg = (((hd - gk) & 3) == 2) ? 2.0f : 1.0f;
    int pair = hd * 4 + gk;
    float la[4], lsum = 0.f;
#pragma unroll
    for (int ch = 0; ch < 4; ++ch) {
      la[ch] = Lpart[((size_t)ch * 16 + pair) * N_TOK + n];
      lsum += la[ch];
    }
    float rs = cg / lsum;
#pragma unroll
    for (int ch = 0; ch < 4; ++ch) {
      half8 v = *(const half8*)(Opart + (((size_t)ch * 16 + pair) * N_TOK + n) * 64 + db);
      float w = la[ch] * rs;
#pragma unroll
      for (int i = 0; i < 8; ++i) acc[i] += w * (float)v[i];
    }
  }
  float* dst = out + (size_t)n * OUTC + hd * 64 + db;
  float4 r0, r1;
  r0.x = acc[0]; r0.y = acc[1]; r0.z = acc[2]; r0.w = acc[3];
  r1.x = acc[4]; r1.y = acc[5]; r1.z = acc[6]; r1.w = acc[7];
  *(float4*)(dst)     = r0;
  *(float4*)(dst + 4) = r1;
}

extern "C" void kernel_launch(void* const* d_in, const int* in_sizes, int n_in,
                              void* d_out, int out_size, void* d_ws, size_t ws_size,
                              hipStream_t stream) {
  (void)in_sizes; (void)n_in; (void)out_size; (void)ws_size;
  const float* x  = (const float*)d_in[0];
  const float* Wq = (const float*)d_in[1];
  const float* bq = (const float*)d_in[2];
  const float* Wk = (const float*)d_in[3];
  const float* bk = (const float*)d_in[4];
  const float* Wv = (const float*)d_in[5];
  const float* bv = (const float*)d_in[6];

  char* ws = (char*)d_ws;
  float*    Lp  = (float*)   (ws);              //   589,824 B
  _Float16* Qh  = (_Float16*)(ws + 1179648);    // 1,179,648 B
  _Float16* KF  = (_Float16*)(ws + 2359296);    // 1,179,648 B (fragment-major)
  float*    VfT = (float*)   (ws + 3538944);    // 2,359,296 B
  _Float16* VF  = (_Float16*)(ws + 5898240);    // 1,179,648 B (fragment-major)
  _Float16* Op  = (_Float16*)(ws + 7077888);    // 18,874,368 B (ends 25,952,256 -- R7-proven range)
  float* out = (float*)d_out;

  k_proj   <<<dim3(36, 4, 3), dim3(256), 0, stream>>>(x, Wq, Wk, Wv, bq, bk, bv, Qh, KF, VfT);
  k_smooth <<<dim3(36, 4), dim3(256), 0, stream>>>(VfT, VF);
  k_flash  <<<dim3(18, 16, 4), dim3(256), 0, stream>>>(Qh, KF, VF, Op, Lp);
  k_combine<<<dim3(288), dim3(256), 0, stream>>>(Op, Lp, out);
}